// Round 1
// baseline (208.447 us; speedup 1.0000x reference)
//
#include <hip/hip_runtime.h>
#include <math.h>

#define NI 256
#define NJ 256
#define NK 1024
#define JCHUNK 64
#define HALO 16
#define FLT_MAX_ 3.402823466e+38f

typedef float float4v __attribute__((ext_vector_type(4)));

__device__ __forceinline__ float finalize(float n, float d) {
    float r = n / d;
    if (isnan(r)) r = 1.0f;
    else if (isinf(r)) r = (r > 0.f) ? FLT_MAX_ : -FLT_MAX_;
    return r;
}

__global__ __launch_bounds__(256, 4)
void semblance_kernel(const float* __restrict__ x, float* __restrict__ out) {
    // LDS: s1^2 and sum-of-squares rows, with 16-float zero halos on each side
    __shared__ __align__(16) float s_num[HALO + NK + HALO];
    __shared__ __align__(16) float s_den[HALO + NK + HALO];

    const int tid  = threadIdx.x;
    const int i    = blockIdx.y;
    const int j0   = blockIdx.x * JCHUNK;
    const int base = tid * 4;          // this thread's first k

    // zero the halos once (front [0,16), back [HALO+NK, HALO+NK+16))
    if (tid < HALO) {
        s_num[tid] = 0.f;
        s_den[tid] = 0.f;
        s_num[HALO + NK + tid] = 0.f;
        s_den[HALO + NK + tid] = 0.f;
    }

    const float* xi = x + (size_t)i * NJ * NK;

    for (int jj = 0; jj < JCHUNK; ++jj) {
        const int j = j0 + jj;

        // ---- j-window (5) sums: s1 = sum x, t1 = sum x^2, zero-padded ----
        float4v s = (float4v)0.0f;
        float4v t = (float4v)0.0f;
        #pragma unroll
        for (int dj = -2; dj <= 2; ++dj) {
            const int jr = j + dj;
            if (jr >= 0 && jr < NJ) {
                float4v v = *(const float4v*)(xi + (size_t)jr * NK + base);
                s += v;
                t += v * v;
            }
        }
        float4v ssq = s * s;
        *(float4v*)(&s_num[HALO + base]) = ssq;
        *(float4v*)(&s_den[HALO + base]) = t;
        __syncthreads();

        // ---- k-window (20, pad (10,9)) sums from LDS ----
        // need floats [base-10, base+12]; load aligned [base-12, base+15]
        float fn[28], fd[28];
        const float4v* pn = (const float4v*)(&s_num[HALO + base - 12]);
        const float4v* pd = (const float4v*)(&s_den[HALO + base - 12]);
        #pragma unroll
        for (int q = 0; q < 7; ++q) {
            float4v a = pn[q];
            float4v b = pd[q];
            #pragma unroll
            for (int e = 0; e < 4; ++e) {
                fn[q * 4 + e] = a[e];
                fd[q * 4 + e] = b[e];
            }
        }

        // base window for e=0: idx [2, 21]
        float wn = 0.f, wd = 0.f;
        #pragma unroll
        for (int idx = 2; idx <= 21; ++idx) {
            wn += fn[idx];
            wd += fd[idx];
        }

        const int jlo = (j - 2 < 0) ? 0 : j - 2;
        const int jhi = (j + 2 > NJ - 1) ? NJ - 1 : j + 2;
        const float norm = (float)(jhi - jlo + 1);

        float4v o;
        o[0] = finalize(wn, wd * norm);
        #pragma unroll
        for (int e = 1; e < 4; ++e) {
            wn += fn[21 + e] - fn[1 + e];
            wd += fd[21 + e] - fd[1 + e];
            o[e] = finalize(wn, wd * norm);
        }

        *(float4v*)(out + ((size_t)i * NJ + j) * NK + base) = o;
        __syncthreads();   // protect LDS before next j's writes
    }
}

extern "C" void kernel_launch(void* const* d_in, const int* in_sizes, int n_in,
                              void* d_out, int out_size, void* d_ws, size_t ws_size,
                              hipStream_t stream) {
    const float* x = (const float*)d_in[0];
    float* out = (float*)d_out;
    dim3 grid(NJ / JCHUNK, NI);   // (4, 256) = 1024 blocks
    semblance_kernel<<<grid, 256, 0, stream>>>(x, out);
}